// Round 13
// baseline (482.201 us; speedup 1.0000x reference)
//
#include <hip/hip_runtime.h>
#include <math.h>

#define D_MODEL 768
#define N_HEAD  12
#define HD      64
#define D_FF    3072
#define SEQ     2048
#define BSZ     4
#define NROWS   (SEQ * BSZ)   // 8192

typedef unsigned short u16;
typedef __attribute__((ext_vector_type(8))) short short8;   // 8 bf16 = 4 VGPRs
typedef __attribute__((ext_vector_type(4))) float float4v;  // MFMA accumulator

enum { FLAG_GELU = 1, FLAG_ABLK = 2, FLAG_CBBLK = 4 };

__device__ __forceinline__ float gelu_exact(float x) {
    return 0.5f * x * (1.0f + erff(x * 0.70710678118654752440f));
}
__device__ __forceinline__ u16 f2b(float f) {      // f32->bf16 RNE
    unsigned u = __builtin_bit_cast(unsigned, f);
    return (u16)((u + 0x7fffu + ((u >> 16) & 1u)) >> 16);
}
__device__ __forceinline__ float b2f(u16 x) {
    return __builtin_bit_cast(float, (unsigned)x << 16);
}
__device__ __forceinline__ void gll16(const u16* g, u16* l) {  // 16B global->LDS
    __builtin_amdgcn_global_load_lds(
        (const __attribute__((address_space(1))) unsigned*)g,
        (__attribute__((address_space(3))) unsigned*)l, 16, 0, 0);
}
// tile-blocked bf16 layout: [M/128][K/32][128][32]; one tile = 8KB contiguous
// = exactly the LDS staging image -> contiguous DRAM streams for GEMM operands.
__device__ __forceinline__ size_t blk_off(int row, int col, int k32) {
    return ((size_t)((row >> 7) * k32 + (col >> 5)) << 12)
         + ((row & 127) << 5) + (col & 31);
}

// ---------------------------------------------------------------------------
// 256x128-tile bf16 GEMM for the big-N GEMMs (QKV N=2304, FFN1 N=3072).
// r12-proven (+20us): staging-traffic bound -> 256-row tile cuts staged
// bytes 25% and doubles MFMA-per-barrier. 512 threads, 8 waves (4M x 2N),
// per-wave 64x64 = verified acc[4][4] fragment code. 2-buffer 1-barrier;
// T2 swizzle (bank conflicts = 0 measured). LDS 48KB -> 3 blocks/CU.
// ---------------------------------------------------------------------------
__global__ __launch_bounds__(512) void gemm_bt256(
    const u16* __restrict__ A,
    const u16* __restrict__ Bt,
    const float* __restrict__ bias,
    u16* __restrict__ Cb, int ldc,
    int K, int flags)
{
    __shared__ u16 Ab[2][256 * 32];
    __shared__ u16 Bb[2][128 * 32];

    const int tid  = threadIdx.x;
    const int lane = tid & 63, wv = tid >> 6;
    const int row0 = blockIdx.x * 256, col0 = blockIdx.y * 128;
    const int mw = (wv & 3) * 64, nw = (wv >> 2) * 64;
    const int fr = lane & 15, hi = lane >> 4;
    const int fk = (hi ^ ((fr >> 1) & 3)) * 8;            // swizzled read chunk
    const int k32 = K >> 5;
    const int nIter = K >> 5;

    auto stage = [&](int buf, int k0) {
        const u16* baseB = Bt + (((size_t)(col0 >> 7) * k32 + (k0 >> 5)) << 12);
        // B: 128x32 = 512 chunks, 1/thread
        {
            const int r = tid >> 2;
            const int sc = (((tid & 3) ^ ((r >> 1) & 3)) * 8);
            gll16(baseB + (size_t)r * 32 + sc, Bb[buf] + (size_t)tid * 8);
        }
        // A: 256x32 = 1024 chunks, 2/thread; rows 128..255 live in the next
        // 128-row A-block (blocked layout)
        #pragma unroll
        for (int i = 0; i < 2; ++i) {
            const int cid = i * 512 + tid;
            const int r = cid >> 2;
            const int sc = (((cid & 3) ^ ((r >> 1) & 3)) * 8);
            const u16* baseA = A +
                (((size_t)((row0 >> 7) + (r >> 7)) * k32 + (k0 >> 5)) << 12);
            gll16(baseA + (size_t)(r & 127) * 32 + sc, Ab[buf] + (size_t)cid * 8);
        }
    };

    float4v acc[4][4];
    #pragma unroll
    for (int i = 0; i < 4; ++i)
        #pragma unroll
        for (int j = 0; j < 4; ++j)
            acc[i][j] = float4v{0.f, 0.f, 0.f, 0.f};

    stage(0, 0);
    for (int it = 0; it < nIter; ++it) {
        const int cur = it & 1;
        __syncthreads();   // buf[cur] staged (drain covers loads issued last iter)
        if (it + 1 < nIter) stage(cur ^ 1, (it + 1) * 32);

        short8 af[4], bfr[4];
        #pragma unroll
        for (int t = 0; t < 4; ++t) {
            af[t]  = *(const short8*)&Ab[cur][(mw + t * 16 + fr) * 32 + fk];
            bfr[t] = *(const short8*)&Bb[cur][(nw + t * 16 + fr) * 32 + fk];
        }
        #pragma unroll
        for (int mt = 0; mt < 4; ++mt)
            #pragma unroll
            for (int nt = 0; nt < 4; ++nt)
                acc[mt][nt] = __builtin_amdgcn_mfma_f32_16x16x32_bf16(
                    af[mt], bfr[nt], acc[mt][nt], 0, 0, 0);
    }

    #pragma unroll
    for (int mt = 0; mt < 4; ++mt)
        #pragma unroll
        for (int nt = 0; nt < 4; ++nt)
            #pragma unroll
            for (int r = 0; r < 4; ++r) {
                const int row = row0 + mw + mt * 16 + hi * 4 + r;
                const int col = col0 + nw + nt * 16 + fr;
                float v = acc[mt][nt][r];
                if (bias)              v += bias[col];
                if (flags & FLAG_GELU) v = gelu_exact(v);
                Cb[blk_off(row, col, ldc >> 5)] = f2b(v);
            }
}

// ---------------------------------------------------------------------------
// 256x64-tile GEMM for N=768 outputs (out-proj, FFN2). v13: same staging
// lever as r12's bt256 -- 512 threads, 8 waves x (32row x 64col), per-wave
// acc[2][4] = the verified gemm_bt64 fragment code. Staged bytes/area -17%
// vs 128x64, MFMA-per-barrier 2x, grid (32,12)=384 blocks of 512thr with
// 40KB LDS -> 3 blocks/CU capacity -> ENTIRE grid resident (no tail).
// B (64x32=256 chunks) staged by waves 0-3 only (wave-uniform predicate).
// ---------------------------------------------------------------------------
__global__ __launch_bounds__(512) void gemm_bt256x64(
    const u16* __restrict__ A, int lda,
    const u16* __restrict__ Bt,
    const float* __restrict__ bias,
    const float* __restrict__ residf, const u16* __restrict__ residb, int ldr,
    float* __restrict__ Cf, u16* __restrict__ Cb, int ldc,
    int K, int flags)
{
    __shared__ u16 Ab[2][256 * 32];
    __shared__ u16 Bb[2][64 * 32];

    const int tid  = threadIdx.x;
    const int lane = tid & 63, wv = tid >> 6;
    const int row0 = blockIdx.x * 256, col0 = blockIdx.y * 64;
    const int mw = wv * 32;
    const int fr = lane & 15, hi = lane >> 4;
    const int fk = (hi ^ ((fr >> 1) & 3)) * 8;            // swizzled read chunk
    const int k32 = K >> 5;
    const int nIter = K >> 5;

    auto stage = [&](int buf, int k0) {
        // B: 64x32 = 256 chunks; waves 0-3 (whole-wave predicate)
        if (tid < 256) {
            const u16* baseB = Bt + (((size_t)(col0 >> 7) * k32 + (k0 >> 5)) << 12)
                                  + ((col0 & 64) << 5);
            const int r = tid >> 2;
            const int sc = (((tid & 3) ^ ((r >> 1) & 3)) * 8);
            gll16(baseB + (size_t)r * 32 + sc, Bb[buf] + (size_t)tid * 8);
        }
        // A: 256x32 = 1024 chunks, 2/thread
        #pragma unroll
        for (int i = 0; i < 2; ++i) {
            const int cid = i * 512 + tid;
            const int r = cid >> 2;
            const int sc = (((cid & 3) ^ ((r >> 1) & 3)) * 8);
            if (flags & FLAG_ABLK) {
                const u16* baseA = A +
                    (((size_t)((row0 >> 7) + (r >> 7)) * k32 + (k0 >> 5)) << 12);
                gll16(baseA + (size_t)(r & 127) * 32 + sc, Ab[buf] + (size_t)cid * 8);
            } else {
                gll16(A + (size_t)(row0 + r) * lda + k0 + sc, Ab[buf] + (size_t)cid * 8);
            }
        }
    };

    float4v acc[2][4];
    #pragma unroll
    for (int i = 0; i < 2; ++i)
        #pragma unroll
        for (int j = 0; j < 4; ++j)
            acc[i][j] = float4v{0.f, 0.f, 0.f, 0.f};

    stage(0, 0);
    for (int it = 0; it < nIter; ++it) {
        const int cur = it & 1;
        __syncthreads();
        if (it + 1 < nIter) stage(cur ^ 1, (it + 1) * 32);

        short8 af[2], bfr[4];
        #pragma unroll
        for (int t = 0; t < 2; ++t)
            af[t] = *(const short8*)&Ab[cur][(mw + t * 16 + fr) * 32 + fk];
        #pragma unroll
        for (int t = 0; t < 4; ++t)
            bfr[t] = *(const short8*)&Bb[cur][(t * 16 + fr) * 32 + fk];
        #pragma unroll
        for (int mt = 0; mt < 2; ++mt)
            #pragma unroll
            for (int nt = 0; nt < 4; ++nt)
                acc[mt][nt] = __builtin_amdgcn_mfma_f32_16x16x32_bf16(
                    af[mt], bfr[nt], acc[mt][nt], 0, 0, 0);
    }

    #pragma unroll
    for (int mt = 0; mt < 2; ++mt)
        #pragma unroll
        for (int nt = 0; nt < 4; ++nt)
            #pragma unroll
            for (int r = 0; r < 4; ++r) {
                const int row = row0 + mw + mt * 16 + hi * 4 + r;
                const int col = col0 + nt * 16 + fr;
                float v = acc[mt][nt][r];
                if (bias)              v += bias[col];
                if (flags & FLAG_GELU) v = gelu_exact(v);
                if (residf)            v += residf[(size_t)row * ldr + col];
                if (residb)            v += b2f(residb[blk_off(row, col, 24)]);
                if (Cf) Cf[(size_t)row * ldc + col] = v;
                if (Cb) Cb[(flags & FLAG_CBBLK) ? blk_off(row, col, ldc >> 5)
                                                : (size_t)row * ldc + col] = f2b(v);
            }
}

// ---------------------------------------------------------------------------
// V transpose: qkv (blocked, k32=72) v-part -> vt[(b*12+h)*64+d][l] row-major
// XOR-swizzled LDS tile (chunk ^ (row>>3), same involution on write and
// read). Unswizzled read had bank = (36j + dr/2)%32 -- lane index vanished
// (288%32==0) -> ~32-way conflict.
// ---------------------------------------------------------------------------
__global__ __launch_bounds__(256) void vt_kernel(
    const u16* __restrict__ qkv, u16* __restrict__ vt)
{
    __shared__ u16 t[64][72];
    const int tid = threadIdx.x;
    const int bh = blockIdx.y, b = bh / N_HEAD, h = bh % N_HEAD;
    const int l0 = blockIdx.x * 64;
    #pragma unroll
    for (int p = 0; p < 2; ++p) {
        const int idx = p * 256 + tid;
        const int lr = idx >> 3, c8 = (idx & 7) * 8;
        const int ch = (idx & 7) ^ ((idx >> 6) & 7);   // chunk ^ (lr>>3)
        *(short8*)&t[lr][ch * 8] = *(const short8*)
            &qkv[blk_off((l0 + lr) * BSZ + b, 1536 + h * 64 + c8, 72)];
    }
    __syncthreads();
    #pragma unroll
    for (int p = 0; p < 2; ++p) {
        const int idx = p * 256 + tid;
        const int dr = idx >> 3, l8 = (idx & 7) * 8;
        const int sc = (((dr >> 3) ^ (idx & 7)) << 3) + (dr & 7); // (l8+j)>>3 == idx&7
        short8 vv;
        #pragma unroll
        for (int j = 0; j < 8; ++j) vv[j] = (short)t[l8 + j][sc];
        *(short8*)&vt[((size_t)(bh * 64 + dr)) * SEQ + l0 + l8] = vv;
    }
}

// ---------------------------------------------------------------------------
// Flash attention, bf16 MFMA, no 1/sqrt(hd) scaling (matches reference).
// r7 config (best known: ~96-99us): round-0 body + bh-major grid (XCD-local
// K/V, FETCH 147->33 MB) + RNE P-store (trunc A/B'd slower in-session).
// ---------------------------------------------------------------------------
__global__ __launch_bounds__(256) void attn_kernel(
    const u16* __restrict__ qkv, const u16* __restrict__ vt,
    u16* __restrict__ o)           // o row-major (NROWS, 768)
{
    __shared__ u16 Kt[2][64 * 64];
    __shared__ u16 Vt[2][64 * 64];
    __shared__ u16 PQ[128 * 72];   // Q staging (packed 128x64), then P (stride 72)

    const int tid  = threadIdx.x;
    const int lane = tid & 63, wv = tid >> 6;
    const int fr = lane & 15, hi = lane >> 4;
    const int bh = blockIdx.x, b = bh / N_HEAD, h = bh % N_HEAD;
    const int q0 = blockIdx.y * 128;

    auto stageKV = [&](int buf, int kt) {
        #pragma unroll
        for (int i = 0; i < 2; ++i) {
            const int cid = i * 256 + wv * 64 + lane;
            const int r = cid >> 3, c = cid & 7;
            const int cs = (c ^ (r & 7)) * 8;   // xor swizzle
            gll16(qkv + blk_off((kt + r) * BSZ + b, 768 + h * 64 + cs, 72),
                  Kt[buf] + (size_t)cid * 8);
            gll16(vt + (size_t)(bh * 64 + r) * SEQ + kt + cs,
                  Vt[buf] + (size_t)cid * 8);
        }
    };

    #pragma unroll
    for (int i = 0; i < 4; ++i) {
        const int cid = i * 256 + wv * 64 + lane;
        const int r = cid >> 3, c = cid & 7;
        gll16(qkv + blk_off((q0 + r) * BSZ + b, h * 64 + ((c ^ (r & 7)) * 8), 72),
              PQ + (size_t)cid * 8);
    }
    stageKV(0, 0);
    __syncthreads();

    short8 qf[2][2];
    #pragma unroll
    for (int mt = 0; mt < 2; ++mt) {
        const int row = wv * 32 + mt * 16 + fr;
        #pragma unroll
        for (int kb = 0; kb < 2; ++kb)
            qf[mt][kb] = *(const short8*)&PQ[row * 64 + (((kb << 2) + hi) ^ (fr & 7)) * 8];
    }

    const short8 ones = {(short)0x3F80, (short)0x3F80, (short)0x3F80, (short)0x3F80,
                         (short)0x3F80, (short)0x3F80, (short)0x3F80, (short)0x3F80};
    float4v oacc[2][4], ls[2];
    #pragma unroll
    for (int mt = 0; mt < 2; ++mt) {
        ls[mt] = float4v{0.f, 0.f, 0.f, 0.f};
        #pragma unroll
        for (int nt = 0; nt < 4; ++nt) oacc[mt][nt] = float4v{0.f, 0.f, 0.f, 0.f};
    }

    for (int it = 0; it < SEQ / 64; ++it) {
        const int cur = it & 1;
        __syncthreads();
        if (it + 1 < SEQ / 64) stageKV(cur ^ 1, (it + 1) * 64);

        float4v s[2][4];
        #pragma unroll
        for (int mt = 0; mt < 2; ++mt)
            #pragma unroll
            for (int nt = 0; nt < 4; ++nt) s[mt][nt] = float4v{0.f, 0.f, 0.f, 0.f};
        #pragma unroll
        for (int kb = 0; kb < 2; ++kb) {
            short8 kfr[4];
            #pragma unroll
            for (int nt = 0; nt < 4; ++nt)
                kfr[nt] = *(const short8*)&Kt[cur][(nt * 16 + fr) * 64 + (((kb << 2) + hi) ^ (fr & 7)) * 8];
            #pragma unroll
            for (int mt = 0; mt < 2; ++mt)
                #pragma unroll
                for (int nt = 0; nt < 4; ++nt)
                    s[mt][nt] = __builtin_amdgcn_mfma_f32_16x16x32_bf16(
                        qf[mt][kb], kfr[nt], s[mt][nt], 0, 0, 0);
        }

        #pragma unroll
        for (int mt = 0; mt < 2; ++mt)
            #pragma unroll
            for (int nt = 0; nt < 4; ++nt)
                #pragma unroll
                for (int r = 0; r < 4; ++r)
                    PQ[(wv * 32 + mt * 16 + hi * 4 + r) * 72 + nt * 16 + fr]
                        = f2b(__expf(s[mt][nt][r] - 16.0f));

        #pragma unroll
        for (int kb = 0; kb < 2; ++kb) {
            short8 pf[2], vfr[4];
            #pragma unroll
            for (int mt = 0; mt < 2; ++mt)
                pf[mt] = *(const short8*)&PQ[(wv * 32 + mt * 16 + fr) * 72 + kb * 32 + hi * 8];
            #pragma unroll
            for (int nt = 0; nt < 4; ++nt)
                vfr[nt] = *(const short8*)&Vt[cur][(nt * 16 + fr) * 64 + (((kb << 2) + hi) ^ (fr & 7)) * 8];
            #pragma unroll
            for (int mt = 0; mt < 2; ++mt) {
                ls[mt] = __builtin_amdgcn_mfma_f32_16x16x32_bf16(pf[mt], ones, ls[mt], 0, 0, 0);
                #pragma unroll
                for (int nt = 0; nt < 4; ++nt)
                    oacc[mt][nt] = __builtin_amdgcn_mfma_f32_16x16x32_bf16(
                        pf[mt], vfr[nt], oacc[mt][nt], 0, 0, 0);
            }
        }
    }

    #pragma unroll
    for (int mt = 0; mt < 2; ++mt)
        #pragma unroll
        for (int r = 0; r < 4; ++r) {
            const int qr = wv * 32 + mt * 16 + hi * 4 + r;
            const float linv = 1.0f / ls[mt][r];
            #pragma unroll
            for (int nt = 0; nt < 4; ++nt)
                o[((size_t)(q0 + qr) * BSZ + b) * D_MODEL + h * 64 + nt * 16 + fr]
                    = f2b(oacc[mt][nt][r] * linv);
        }
}

// ---------------------------------------------------------------------------
// LayerNorm over D_MODEL=768 -- r7 version (block-per-row, LDS partials).
// (r8's wave-per-row rewrite regressed FFN1; keep this one.)
// ---------------------------------------------------------------------------
__global__ __launch_bounds__(256) void ln_kernel(
    const float* __restrict__ x, float* __restrict__ outf, u16* __restrict__ outb,
    const float* __restrict__ g, const float* __restrict__ be)
{
    const int row = blockIdx.x;
    const int tid = threadIdx.x;
    const float* xr = x + (size_t)row * D_MODEL;
    float v[3];
    float s = 0.0f, sq = 0.0f;
    #pragma unroll
    for (int j = 0; j < 3; ++j) {
        v[j] = xr[tid + 256 * j];
        s  += v[j];
        sq += v[j] * v[j];
    }
    #pragma unroll
    for (int off = 32; off > 0; off >>= 1) {
        s  += __shfl_down(s, off);
        sq += __shfl_down(sq, off);
    }
    __shared__ float ws_[8], wq_[8];
    if ((tid & 63) == 0) { ws_[tid >> 6] = s; wq_[tid >> 6] = sq; }
    __syncthreads();
    if (tid == 0) {
        float S = 0.0f, Q = 0.0f;
        #pragma unroll
        for (int w = 0; w < 4; ++w) { S += ws_[w]; Q += wq_[w]; }
        ws_[4] = S; wq_[4] = Q;
    }
    __syncthreads();
    const float mu   = ws_[4] * (1.0f / D_MODEL);
    const float var  = wq_[4] * (1.0f / D_MODEL) - mu * mu;
    const float rstd = rsqrtf(var + 1e-5f);
    #pragma unroll
    for (int j = 0; j < 3; ++j) {
        const int c = tid + 256 * j;
        const float y = (v[j] - mu) * rstd * g[c] + be[c];
        if (outf) outf[(size_t)row * D_MODEL + c] = y;
        if (outb) outb[blk_off(row, c, 24)] = f2b(y);
    }
}

// ---------------------------------------------------------------------------
// Batched prologue: 6 weight transposes + conv_bf_blk + pack_bias in ONE
// launch (9993 blocks, branch on blockIdx.x) -- removes 7 launch/drain
// boundaries. All sub-tasks independent; __syncthreads only in the
// transpose path, which is block-uniform.
// ---------------------------------------------------------------------------
__device__ __forceinline__ void transpose_body(
    const float* __restrict__ in, u16* __restrict__ out, int R, int Cn,
    int bx, int by, int tid, float (*t)[33])
{
    const int c0 = bx * 32, r0 = by * 32;
    const int tx = tid & 31, ty = tid >> 5;
    #pragma unroll
    for (int i = 0; i < 4; ++i)
        t[ty + i * 8][tx] = in[(size_t)(r0 + ty + i * 8) * Cn + c0 + tx];
    __syncthreads();
    const int k32 = R >> 5;
    #pragma unroll
    for (int i = 0; i < 4; ++i)
        out[blk_off(c0 + ty + i * 8, r0 + tx, k32)] = f2b(t[tx][ty + i * 8]);
}

__global__ __launch_bounds__(256) void prep_kernel(
    const float* __restrict__ Wq, const float* __restrict__ Wk,
    const float* __restrict__ Wv, const float* __restrict__ Wo,
    const float* __restrict__ W1, const float* __restrict__ W2,
    const float* __restrict__ src,
    const float* __restrict__ bq, const float* __restrict__ bk,
    const float* __restrict__ bv,
    u16* __restrict__ WqkvT, u16* __restrict__ WoT,
    u16* __restrict__ W1T, u16* __restrict__ W2T,
    u16* __restrict__ srcb, float* __restrict__ bqkv)
{
    __shared__ float t[32][33];
    const int id = blockIdx.x, tid = threadIdx.x;
    if (id < 6912) {                       // weight transposes
        const float* tin; u16* tout; int R, Cn, bx, by;
        if (id < 2304) {                   // Wq/Wk/Wv/Wo: 4 x (24x24 = 576)
            const int z = id / 576, i = id - z * 576;
            tin  = (z == 0) ? Wq : (z == 1) ? Wk : (z == 2) ? Wv : Wo;
            tout = (z == 3) ? WoT : WqkvT + z * 768 * 768;
            R = 768; Cn = 768; bx = i % 24; by = i / 24;
        } else if (id < 4608) {            // W1: 96x24
            const int i = id - 2304;
            tin = W1; tout = W1T; R = 768; Cn = 3072; bx = i % 96; by = i / 96;
        } else {                           // W2: 24x96
            const int i = id - 4608;
            tin = W2; tout = W2T; R = 3072; Cn = 768; bx = i % 24; by = i / 24;
        }
        transpose_body(tin, tout, R, Cn, bx, by, tid, t);
    } else if (id < 9984) {                // conv_bf_blk: 3072 blocks
        const int i = (id - 6912) * 256 + tid;
        const int row = i / 96;
        const int c8  = (i - row * 96) * 8;
        const float4 a = *(const float4*)&src[(size_t)row * 768 + c8];
        const float4 b = *(const float4*)&src[(size_t)row * 768 + c8 + 4];
        uint4 pk;
        pk.x = (unsigned)f2b(a.x) | ((unsigned)f2b(a.y) << 16);
        pk.y = (unsigned)f2b(a.z) | ((unsigned)f2b(a.w) << 16);
        pk.z = (unsigned)f2b(b.x) | ((unsigned)f2b(b.y) << 16);
        pk.w = (unsigned)f2b(b.z) | ((unsigned)f2b(b.w) << 16);
        *(uint4*)&srcb[blk_off(row, c8, 24)] = pk;
    } else {                               // pack_bias: 9 blocks
        const int i = (id - 9984) * 256 + tid;
        if (i < 2304)
            bqkv[i] = (i < 768) ? bq[i] : (i < 1536) ? bk[i - 768] : bv[i - 1536];
    }
}

extern "C" void kernel_launch(void* const* d_in, const int* in_sizes, int n_in,
                              void* d_out, int out_size, void* d_ws, size_t ws_size,
                              hipStream_t stream)
{
    (void)in_sizes; (void)n_in; (void)out_size; (void)ws_size;
    const float* src = (const float*)d_in[0];
    const float* Wq  = (const float*)d_in[1];
    const float* bq  = (const float*)d_in[2];
    const float* Wk  = (const float*)d_in[3];
    const float* bk  = (const float*)d_in[4];
    const float* Wv  = (const float*)d_in[5];
    const float* bv  = (const float*)d_in[6];
    const float* Wo  = (const float*)d_in[7];
    const float* bo  = (const float*)d_in[8];
    const float* W1  = (const float*)d_in[9];
    const float* b1  = (const float*)d_in[10];
    const float* W2  = (const float*)d_in[11];
    const float* b2  = (const float*)d_in[12];
    const float* g1  = (const float*)d_in[13];
    const float* be1 = (const float*)d_in[14];
    const float* g2  = (const float*)d_in[15];
    const float* be2 = (const float*)d_in[16];
    float* out = (float*)d_out;

    // ---- workspace layout (~77 MB peak) ----
    char* w = (char*)d_ws;
    u16* WqkvT = (u16*)w; w += (size_t)2304 * 768 * 2;
    u16* WoT   = (u16*)w; w += (size_t)768 * 768 * 2;
    u16* W1T   = (u16*)w; w += (size_t)D_FF * 768 * 2;
    u16* W2T   = (u16*)w; w += (size_t)768 * D_FF * 2;
    float* bqkv = (float*)w; w += 2304 * 4 + 64;
    char* A0 = w; w += (size_t)NROWS * 768 * 2;          // 12.58 MB
    char* A1 = w; w += (size_t)NROWS * 2304 * 2;         // 37.75 MB
    char* A2 = w; w += (size_t)NROWS * 768 * 2;          // 12.58 MB
    u16*   srcb  = (u16*)A0;    // blocked; dead after QKV gemm
    u16*   vtb   = (u16*)A0;    // alias: live during attention
    u16*   qkvb  = (u16*)A1;    // blocked; dead after attention
    float* sum   = (float*)A1;  // alias: out-proj f32 out
    u16*   attnb = (u16*)A2;    // row-major; dead after out-proj
    u16*   x1b   = (u16*)A2;    // alias: LN1 blocked bf16 out
    u16*   hb    = (u16*)A0;    // alias: blocked FFN hidden spans A0+A1

    const dim3 blk(256);
    const dim3 blk512(512);

    // single batched prologue launch (was 8 kernels)
    prep_kernel<<<dim3(9993), blk, 0, stream>>>(
        Wq, Wk, Wv, Wo, W1, W2, src, bq, bk, bv,
        WqkvT, WoT, W1T, W2T, srcb, bqkv);

    // fused QKV projection: 256x128 tiles (32x18 = 576 blocks)
    gemm_bt256<<<dim3(32, 18), blk512, 0, stream>>>(srcb, WqkvT, bqkv,
        qkvb, 2304, 768, FLAG_ABLK | FLAG_CBBLK);

    // V transpose, then flash attention (bh-major grid: wgid%8==bh%8 -> one XCD
    // owns all 16 q-blocks of a head -> K/V L2-resident)
    vt_kernel<<<dim3(32, 48), blk, 0, stream>>>(qkvb, vtb);
    attn_kernel<<<dim3(BSZ * N_HEAD, SEQ / 128), blk, 0, stream>>>(qkvb, vtb, attnb);

    // out-proj (+src residual) -> sum f32; LN1 -> x1b (blocked bf16)
    // 256x64 tiles: 384 blocks of 512thr, whole grid resident
    gemm_bt256x64<<<dim3(32, 12), blk512, 0, stream>>>(attnb, 768, WoT, bo,
        src, nullptr, 768, sum, nullptr, 768, 768, 0);
    ln_kernel<<<dim3(NROWS), blk, 0, stream>>>(sum, nullptr, x1b, g1, be1);

    // FFN: hb = gelu(x1 @ W1 + b1) blocked (256x128 tiles, 32x24 = 768 blocks);
    // out = hb @ W2 + b2 + x1 (256x64 tiles)
    gemm_bt256<<<dim3(32, 24), blk512, 0, stream>>>(x1b, W1T, b1,
        hb, 3072, 768, FLAG_GELU | FLAG_ABLK | FLAG_CBBLK);
    gemm_bt256x64<<<dim3(32, 12), blk512, 0, stream>>>(hb, 0, W2T, b2,
        nullptr, x1b, 768, out, nullptr, 768, 3072, FLAG_ABLK);

    // final LN in place
    ln_kernel<<<dim3(NROWS), blk, 0, stream>>>(out, out, nullptr, g2, be2);
}

// Round 14
// 465.678 us; speedup vs baseline: 1.0355x; 1.0355x over previous
//
#include <hip/hip_runtime.h>
#include <math.h>

#define D_MODEL 768
#define N_HEAD  12
#define HD      64
#define D_FF    3072
#define SEQ     2048
#define BSZ     4
#define NROWS   (SEQ * BSZ)   // 8192

typedef unsigned short u16;
typedef __attribute__((ext_vector_type(8))) short short8;   // 8 bf16 = 4 VGPRs
typedef __attribute__((ext_vector_type(4))) float float4v;  // MFMA accumulator

enum { FLAG_GELU = 1, FLAG_ABLK = 2, FLAG_CBBLK = 4 };

__device__ __forceinline__ float gelu_exact(float x) {
    return 0.5f * x * (1.0f + erff(x * 0.70710678118654752440f));
}
__device__ __forceinline__ u16 f2b(float f) {      // f32->bf16 RNE
    unsigned u = __builtin_bit_cast(unsigned, f);
    return (u16)((u + 0x7fffu + ((u >> 16) & 1u)) >> 16);
}
__device__ __forceinline__ float b2f(u16 x) {
    return __builtin_bit_cast(float, (unsigned)x << 16);
}
__device__ __forceinline__ void gll16(const u16* g, u16* l) {  // 16B global->LDS
    __builtin_amdgcn_global_load_lds(
        (const __attribute__((address_space(1))) unsigned*)g,
        (__attribute__((address_space(3))) unsigned*)l, 16, 0, 0);
}
// tile-blocked bf16 layout: [M/128][K/32][128][32]; one tile = 8KB contiguous
// = exactly the LDS staging image -> contiguous DRAM streams for GEMM operands.
__device__ __forceinline__ size_t blk_off(int row, int col, int k32) {
    return ((size_t)((row >> 7) * k32 + (col >> 5)) << 12)
         + ((row & 127) << 5) + (col & 31);
}

// ---------------------------------------------------------------------------
// 256x128-tile bf16 GEMM for the big-N GEMMs (QKV N=2304, FFN1 N=3072).
// r12-proven (+20us): staging-traffic bound -> 256-row tile cuts staged
// bytes 25% and doubles MFMA-per-barrier. 512 threads, 8 waves (4M x 2N),
// per-wave 64x64 = verified acc[4][4] fragment code. 2-buffer 1-barrier;
// T2 swizzle (bank conflicts = 0 measured). LDS 48KB -> 3 blocks/CU.
// (r13 tried 256x64 for the N=768 GEMMs: -2.8% -- more, smaller blocks win
// there; tile choice is shape-dependent, both directions measured.)
// ---------------------------------------------------------------------------
__global__ __launch_bounds__(512) void gemm_bt256(
    const u16* __restrict__ A,
    const u16* __restrict__ Bt,
    const float* __restrict__ bias,
    u16* __restrict__ Cb, int ldc,
    int K, int flags)
{
    __shared__ u16 Ab[2][256 * 32];
    __shared__ u16 Bb[2][128 * 32];

    const int tid  = threadIdx.x;
    const int lane = tid & 63, wv = tid >> 6;
    const int row0 = blockIdx.x * 256, col0 = blockIdx.y * 128;
    const int mw = (wv & 3) * 64, nw = (wv >> 2) * 64;
    const int fr = lane & 15, hi = lane >> 4;
    const int fk = (hi ^ ((fr >> 1) & 3)) * 8;            // swizzled read chunk
    const int k32 = K >> 5;
    const int nIter = K >> 5;

    auto stage = [&](int buf, int k0) {
        const u16* baseB = Bt + (((size_t)(col0 >> 7) * k32 + (k0 >> 5)) << 12);
        // B: 128x32 = 512 chunks, 1/thread
        {
            const int r = tid >> 2;
            const int sc = (((tid & 3) ^ ((r >> 1) & 3)) * 8);
            gll16(baseB + (size_t)r * 32 + sc, Bb[buf] + (size_t)tid * 8);
        }
        // A: 256x32 = 1024 chunks, 2/thread; rows 128..255 live in the next
        // 128-row A-block (blocked layout)
        #pragma unroll
        for (int i = 0; i < 2; ++i) {
            const int cid = i * 512 + tid;
            const int r = cid >> 2;
            const int sc = (((cid & 3) ^ ((r >> 1) & 3)) * 8);
            const u16* baseA = A +
                (((size_t)((row0 >> 7) + (r >> 7)) * k32 + (k0 >> 5)) << 12);
            gll16(baseA + (size_t)(r & 127) * 32 + sc, Ab[buf] + (size_t)cid * 8);
        }
    };

    float4v acc[4][4];
    #pragma unroll
    for (int i = 0; i < 4; ++i)
        #pragma unroll
        for (int j = 0; j < 4; ++j)
            acc[i][j] = float4v{0.f, 0.f, 0.f, 0.f};

    stage(0, 0);
    for (int it = 0; it < nIter; ++it) {
        const int cur = it & 1;
        __syncthreads();   // buf[cur] staged (drain covers loads issued last iter)
        if (it + 1 < nIter) stage(cur ^ 1, (it + 1) * 32);

        short8 af[4], bfr[4];
        #pragma unroll
        for (int t = 0; t < 4; ++t) {
            af[t]  = *(const short8*)&Ab[cur][(mw + t * 16 + fr) * 32 + fk];
            bfr[t] = *(const short8*)&Bb[cur][(nw + t * 16 + fr) * 32 + fk];
        }
        #pragma unroll
        for (int mt = 0; mt < 4; ++mt)
            #pragma unroll
            for (int nt = 0; nt < 4; ++nt)
                acc[mt][nt] = __builtin_amdgcn_mfma_f32_16x16x32_bf16(
                    af[mt], bfr[nt], acc[mt][nt], 0, 0, 0);
    }

    #pragma unroll
    for (int mt = 0; mt < 4; ++mt)
        #pragma unroll
        for (int nt = 0; nt < 4; ++nt)
            #pragma unroll
            for (int r = 0; r < 4; ++r) {
                const int row = row0 + mw + mt * 16 + hi * 4 + r;
                const int col = col0 + nw + nt * 16 + fr;
                float v = acc[mt][nt][r];
                if (bias)              v += bias[col];
                if (flags & FLAG_GELU) v = gelu_exact(v);
                Cb[blk_off(row, col, ldc >> 5)] = f2b(v);
            }
}

// ---------------------------------------------------------------------------
// 128x64-tile GEMM for N=768 outputs (out-proj, FFN2). 768 blocks = 3/CU.
// r7-proven; T2 XOR-swizzle kept (neutral but bit-exact-verified).
// ---------------------------------------------------------------------------
__global__ __launch_bounds__(256) void gemm_bt64(
    const u16* __restrict__ A, int lda,
    const u16* __restrict__ Bt,
    const float* __restrict__ bias,
    const float* __restrict__ residf, const u16* __restrict__ residb, int ldr,
    float* __restrict__ Cf, u16* __restrict__ Cb, int ldc,
    int K, int flags)
{
    __shared__ u16 Ab[2][128 * 32];
    __shared__ u16 Bb[2][64 * 32];

    const int tid  = threadIdx.x;
    const int lane = tid & 63, wv = tid >> 6;
    const int row0 = blockIdx.x * 128, col0 = blockIdx.y * 64;
    const int mw = wv * 32;
    const int fr = lane & 15, hi = lane >> 4;
    const int fk = (hi ^ ((fr >> 1) & 3)) * 8;            // swizzled read chunk
    const int k32 = K >> 5;
    const int nIter = K >> 5;

    auto stage = [&](int buf, int k0) {
        const u16* baseB = Bt + (((size_t)(col0 >> 7) * k32 + (k0 >> 5)) << 12)
                              + ((col0 & 64) << 5);
        {
            const int r = tid >> 2;
            const int sc = (((tid & 3) ^ ((r >> 1) & 3)) * 8);
            gll16(baseB + (size_t)r * 32 + sc, Bb[buf] + (size_t)tid * 8);
        }
        if (flags & FLAG_ABLK) {
            const u16* baseA = A + (((size_t)(row0 >> 7) * k32 + (k0 >> 5)) << 12);
            #pragma unroll
            for (int i = 0; i < 2; ++i) {
                const int cid = i * 256 + tid;
                const int r = cid >> 2;
                const int sc = (((cid & 3) ^ ((r >> 1) & 3)) * 8);
                gll16(baseA + (size_t)r * 32 + sc, Ab[buf] + (size_t)cid * 8);
            }
        } else {
            #pragma unroll
            for (int i = 0; i < 2; ++i) {
                const int cid = i * 256 + tid;
                const int r = cid >> 2;
                const int sc = (((cid & 3) ^ ((r >> 1) & 3)) * 8);
                gll16(A + (size_t)(row0 + r) * lda + k0 + sc, Ab[buf] + (size_t)cid * 8);
            }
        }
    };

    float4v acc[2][4];
    #pragma unroll
    for (int i = 0; i < 2; ++i)
        #pragma unroll
        for (int j = 0; j < 4; ++j)
            acc[i][j] = float4v{0.f, 0.f, 0.f, 0.f};

    stage(0, 0);
    for (int it = 0; it < nIter; ++it) {
        const int cur = it & 1;
        __syncthreads();
        if (it + 1 < nIter) stage(cur ^ 1, (it + 1) * 32);

        short8 af[2], bfr[4];
        #pragma unroll
        for (int t = 0; t < 2; ++t)
            af[t] = *(const short8*)&Ab[cur][(mw + t * 16 + fr) * 32 + fk];
        #pragma unroll
        for (int t = 0; t < 4; ++t)
            bfr[t] = *(const short8*)&Bb[cur][(t * 16 + fr) * 32 + fk];
        #pragma unroll
        for (int mt = 0; mt < 2; ++mt)
            #pragma unroll
            for (int nt = 0; nt < 4; ++nt)
                acc[mt][nt] = __builtin_amdgcn_mfma_f32_16x16x32_bf16(
                    af[mt], bfr[nt], acc[mt][nt], 0, 0, 0);
    }

    #pragma unroll
    for (int mt = 0; mt < 2; ++mt)
        #pragma unroll
        for (int nt = 0; nt < 4; ++nt)
            #pragma unroll
            for (int r = 0; r < 4; ++r) {
                const int row = row0 + mw + mt * 16 + hi * 4 + r;
                const int col = col0 + nt * 16 + fr;
                float v = acc[mt][nt][r];
                if (bias)              v += bias[col];
                if (flags & FLAG_GELU) v = gelu_exact(v);
                if (residf)            v += residf[(size_t)row * ldr + col];
                if (residb)            v += b2f(residb[blk_off(row, col, 24)]);
                if (Cf) Cf[(size_t)row * ldc + col] = v;
                if (Cb) Cb[(flags & FLAG_CBBLK) ? blk_off(row, col, ldc >> 5)
                                                : (size_t)row * ldc + col] = f2b(v);
            }
}

// ---------------------------------------------------------------------------
// V transpose: qkv (blocked, k32=72) v-part -> vt[(b*12+h)*64+d][l] row-major
// XOR-swizzled LDS tile (chunk ^ (row>>3), same involution on write and
// read). Unswizzled read had bank = (36j + dr/2)%32 -- lane index vanished
// (288%32==0) -> ~32-way conflict.
// ---------------------------------------------------------------------------
__global__ __launch_bounds__(256) void vt_kernel(
    const u16* __restrict__ qkv, u16* __restrict__ vt)
{
    __shared__ u16 t[64][72];
    const int tid = threadIdx.x;
    const int bh = blockIdx.y, b = bh / N_HEAD, h = bh % N_HEAD;
    const int l0 = blockIdx.x * 64;
    #pragma unroll
    for (int p = 0; p < 2; ++p) {
        const int idx = p * 256 + tid;
        const int lr = idx >> 3, c8 = (idx & 7) * 8;
        const int ch = (idx & 7) ^ ((idx >> 6) & 7);   // chunk ^ (lr>>3)
        *(short8*)&t[lr][ch * 8] = *(const short8*)
            &qkv[blk_off((l0 + lr) * BSZ + b, 1536 + h * 64 + c8, 72)];
    }
    __syncthreads();
    #pragma unroll
    for (int p = 0; p < 2; ++p) {
        const int idx = p * 256 + tid;
        const int dr = idx >> 3, l8 = (idx & 7) * 8;
        const int sc = (((dr >> 3) ^ (idx & 7)) << 3) + (dr & 7); // (l8+j)>>3 == idx&7
        short8 vv;
        #pragma unroll
        for (int j = 0; j < 8; ++j) vv[j] = (short)t[l8 + j][sc];
        *(short8*)&vt[((size_t)(bh * 64 + dr)) * SEQ + l0 + l8] = vv;
    }
}

// ---------------------------------------------------------------------------
// Flash attention, bf16 MFMA, no 1/sqrt(hd) scaling (matches reference).
// r7 config (best known: ~96-99us): round-0 body + bh-major grid (XCD-local
// K/V, FETCH 147->33 MB) + RNE P-store (trunc A/B'd slower in-session).
// ---------------------------------------------------------------------------
__global__ __launch_bounds__(256) void attn_kernel(
    const u16* __restrict__ qkv, const u16* __restrict__ vt,
    u16* __restrict__ o)           // o row-major (NROWS, 768)
{
    __shared__ u16 Kt[2][64 * 64];
    __shared__ u16 Vt[2][64 * 64];
    __shared__ u16 PQ[128 * 72];   // Q staging (packed 128x64), then P (stride 72)

    const int tid  = threadIdx.x;
    const int lane = tid & 63, wv = tid >> 6;
    const int fr = lane & 15, hi = lane >> 4;
    const int bh = blockIdx.x, b = bh / N_HEAD, h = bh % N_HEAD;
    const int q0 = blockIdx.y * 128;

    auto stageKV = [&](int buf, int kt) {
        #pragma unroll
        for (int i = 0; i < 2; ++i) {
            const int cid = i * 256 + wv * 64 + lane;
            const int r = cid >> 3, c = cid & 7;
            const int cs = (c ^ (r & 7)) * 8;   // xor swizzle
            gll16(qkv + blk_off((kt + r) * BSZ + b, 768 + h * 64 + cs, 72),
                  Kt[buf] + (size_t)cid * 8);
            gll16(vt + (size_t)(bh * 64 + r) * SEQ + kt + cs,
                  Vt[buf] + (size_t)cid * 8);
        }
    };

    #pragma unroll
    for (int i = 0; i < 4; ++i) {
        const int cid = i * 256 + wv * 64 + lane;
        const int r = cid >> 3, c = cid & 7;
        gll16(qkv + blk_off((q0 + r) * BSZ + b, h * 64 + ((c ^ (r & 7)) * 8), 72),
              PQ + (size_t)cid * 8);
    }
    stageKV(0, 0);
    __syncthreads();

    short8 qf[2][2];
    #pragma unroll
    for (int mt = 0; mt < 2; ++mt) {
        const int row = wv * 32 + mt * 16 + fr;
        #pragma unroll
        for (int kb = 0; kb < 2; ++kb)
            qf[mt][kb] = *(const short8*)&PQ[row * 64 + (((kb << 2) + hi) ^ (fr & 7)) * 8];
    }

    const short8 ones = {(short)0x3F80, (short)0x3F80, (short)0x3F80, (short)0x3F80,
                         (short)0x3F80, (short)0x3F80, (short)0x3F80, (short)0x3F80};
    float4v oacc[2][4], ls[2];
    #pragma unroll
    for (int mt = 0; mt < 2; ++mt) {
        ls[mt] = float4v{0.f, 0.f, 0.f, 0.f};
        #pragma unroll
        for (int nt = 0; nt < 4; ++nt) oacc[mt][nt] = float4v{0.f, 0.f, 0.f, 0.f};
    }

    for (int it = 0; it < SEQ / 64; ++it) {
        const int cur = it & 1;
        __syncthreads();
        if (it + 1 < SEQ / 64) stageKV(cur ^ 1, (it + 1) * 64);

        float4v s[2][4];
        #pragma unroll
        for (int mt = 0; mt < 2; ++mt)
            #pragma unroll
            for (int nt = 0; nt < 4; ++nt) s[mt][nt] = float4v{0.f, 0.f, 0.f, 0.f};
        #pragma unroll
        for (int kb = 0; kb < 2; ++kb) {
            short8 kfr[4];
            #pragma unroll
            for (int nt = 0; nt < 4; ++nt)
                kfr[nt] = *(const short8*)&Kt[cur][(nt * 16 + fr) * 64 + (((kb << 2) + hi) ^ (fr & 7)) * 8];
            #pragma unroll
            for (int mt = 0; mt < 2; ++mt)
                #pragma unroll
                for (int nt = 0; nt < 4; ++nt)
                    s[mt][nt] = __builtin_amdgcn_mfma_f32_16x16x32_bf16(
                        qf[mt][kb], kfr[nt], s[mt][nt], 0, 0, 0);
        }

        #pragma unroll
        for (int mt = 0; mt < 2; ++mt)
            #pragma unroll
            for (int nt = 0; nt < 4; ++nt)
                #pragma unroll
                for (int r = 0; r < 4; ++r)
                    PQ[(wv * 32 + mt * 16 + hi * 4 + r) * 72 + nt * 16 + fr]
                        = f2b(__expf(s[mt][nt][r] - 16.0f));

        #pragma unroll
        for (int kb = 0; kb < 2; ++kb) {
            short8 pf[2], vfr[4];
            #pragma unroll
            for (int mt = 0; mt < 2; ++mt)
                pf[mt] = *(const short8*)&PQ[(wv * 32 + mt * 16 + fr) * 72 + kb * 32 + hi * 8];
            #pragma unroll
            for (int nt = 0; nt < 4; ++nt)
                vfr[nt] = *(const short8*)&Vt[cur][(nt * 16 + fr) * 64 + (((kb << 2) + hi) ^ (fr & 7)) * 8];
            #pragma unroll
            for (int mt = 0; mt < 2; ++mt) {
                ls[mt] = __builtin_amdgcn_mfma_f32_16x16x32_bf16(pf[mt], ones, ls[mt], 0, 0, 0);
                #pragma unroll
                for (int nt = 0; nt < 4; ++nt)
                    oacc[mt][nt] = __builtin_amdgcn_mfma_f32_16x16x32_bf16(
                        pf[mt], vfr[nt], oacc[mt][nt], 0, 0, 0);
            }
        }
    }

    #pragma unroll
    for (int mt = 0; mt < 2; ++mt)
        #pragma unroll
        for (int r = 0; r < 4; ++r) {
            const int qr = wv * 32 + mt * 16 + hi * 4 + r;
            const float linv = 1.0f / ls[mt][r];
            #pragma unroll
            for (int nt = 0; nt < 4; ++nt)
                o[((size_t)(q0 + qr) * BSZ + b) * D_MODEL + h * 64 + nt * 16 + fr]
                    = f2b(oacc[mt][nt][r] * linv);
        }
}

// ---------------------------------------------------------------------------
// LayerNorm over D_MODEL=768 -- r7 version (block-per-row, LDS partials).
// (r8's wave-per-row rewrite regressed FFN1; keep this one.)
// ---------------------------------------------------------------------------
__global__ __launch_bounds__(256) void ln_kernel(
    const float* __restrict__ x, float* __restrict__ outf, u16* __restrict__ outb,
    const float* __restrict__ g, const float* __restrict__ be)
{
    const int row = blockIdx.x;
    const int tid = threadIdx.x;
    const float* xr = x + (size_t)row * D_MODEL;
    float v[3];
    float s = 0.0f, sq = 0.0f;
    #pragma unroll
    for (int j = 0; j < 3; ++j) {
        v[j] = xr[tid + 256 * j];
        s  += v[j];
        sq += v[j] * v[j];
    }
    #pragma unroll
    for (int off = 32; off > 0; off >>= 1) {
        s  += __shfl_down(s, off);
        sq += __shfl_down(sq, off);
    }
    __shared__ float ws_[8], wq_[8];
    if ((tid & 63) == 0) { ws_[tid >> 6] = s; wq_[tid >> 6] = sq; }
    __syncthreads();
    if (tid == 0) {
        float S = 0.0f, Q = 0.0f;
        #pragma unroll
        for (int w = 0; w < 4; ++w) { S += ws_[w]; Q += wq_[w]; }
        ws_[4] = S; wq_[4] = Q;
    }
    __syncthreads();
    const float mu   = ws_[4] * (1.0f / D_MODEL);
    const float var  = wq_[4] * (1.0f / D_MODEL) - mu * mu;
    const float rstd = rsqrtf(var + 1e-5f);
    #pragma unroll
    for (int j = 0; j < 3; ++j) {
        const int c = tid + 256 * j;
        const float y = (v[j] - mu) * rstd * g[c] + be[c];
        if (outf) outf[(size_t)row * D_MODEL + c] = y;
        if (outb) outb[blk_off(row, c, 24)] = f2b(y);
    }
}

// ---------------------------------------------------------------------------
// Batched prologue: 6 weight transposes + conv_bf_blk + pack_bias in ONE
// launch (9993 blocks, branch on blockIdx.x) -- removes 7 launch/drain
// boundaries. All sub-tasks independent; __syncthreads only in the
// transpose path, which is block-uniform.
// ---------------------------------------------------------------------------
__device__ __forceinline__ void transpose_body(
    const float* __restrict__ in, u16* __restrict__ out, int R, int Cn,
    int bx, int by, int tid, float (*t)[33])
{
    const int c0 = bx * 32, r0 = by * 32;
    const int tx = tid & 31, ty = tid >> 5;
    #pragma unroll
    for (int i = 0; i < 4; ++i)
        t[ty + i * 8][tx] = in[(size_t)(r0 + ty + i * 8) * Cn + c0 + tx];
    __syncthreads();
    const int k32 = R >> 5;
    #pragma unroll
    for (int i = 0; i < 4; ++i)
        out[blk_off(c0 + ty + i * 8, r0 + tx, k32)] = f2b(t[tx][ty + i * 8]);
}

__global__ __launch_bounds__(256) void prep_kernel(
    const float* __restrict__ Wq, const float* __restrict__ Wk,
    const float* __restrict__ Wv, const float* __restrict__ Wo,
    const float* __restrict__ W1, const float* __restrict__ W2,
    const float* __restrict__ src,
    const float* __restrict__ bq, const float* __restrict__ bk,
    const float* __restrict__ bv,
    u16* __restrict__ WqkvT, u16* __restrict__ WoT,
    u16* __restrict__ W1T, u16* __restrict__ W2T,
    u16* __restrict__ srcb, float* __restrict__ bqkv)
{
    __shared__ float t[32][33];
    const int id = blockIdx.x, tid = threadIdx.x;
    if (id < 6912) {                       // weight transposes
        const float* tin; u16* tout; int R, Cn, bx, by;
        if (id < 2304) {                   // Wq/Wk/Wv/Wo: 4 x (24x24 = 576)
            const int z = id / 576, i = id - z * 576;
            tin  = (z == 0) ? Wq : (z == 1) ? Wk : (z == 2) ? Wv : Wo;
            tout = (z == 3) ? WoT : WqkvT + z * 768 * 768;
            R = 768; Cn = 768; bx = i % 24; by = i / 24;
        } else if (id < 4608) {            // W1: 96x24
            const int i = id - 2304;
            tin = W1; tout = W1T; R = 768; Cn = 3072; bx = i % 96; by = i / 96;
        } else {                           // W2: 24x96
            const int i = id - 4608;
            tin = W2; tout = W2T; R = 3072; Cn = 768; bx = i % 24; by = i / 24;
        }
        transpose_body(tin, tout, R, Cn, bx, by, tid, t);
    } else if (id < 9984) {                // conv_bf_blk: 3072 blocks
        const int i = (id - 6912) * 256 + tid;
        const int row = i / 96;
        const int c8  = (i - row * 96) * 8;
        const float4 a = *(const float4*)&src[(size_t)row * 768 + c8];
        const float4 b = *(const float4*)&src[(size_t)row * 768 + c8 + 4];
        uint4 pk;
        pk.x = (unsigned)f2b(a.x) | ((unsigned)f2b(a.y) << 16);
        pk.y = (unsigned)f2b(a.z) | ((unsigned)f2b(a.w) << 16);
        pk.z = (unsigned)f2b(b.x) | ((unsigned)f2b(b.y) << 16);
        pk.w = (unsigned)f2b(b.z) | ((unsigned)f2b(b.w) << 16);
        *(uint4*)&srcb[blk_off(row, c8, 24)] = pk;
    } else {                               // pack_bias: 9 blocks
        const int i = (id - 9984) * 256 + tid;
        if (i < 2304)
            bqkv[i] = (i < 768) ? bq[i] : (i < 1536) ? bk[i - 768] : bv[i - 1536];
    }
}

extern "C" void kernel_launch(void* const* d_in, const int* in_sizes, int n_in,
                              void* d_out, int out_size, void* d_ws, size_t ws_size,
                              hipStream_t stream)
{
    (void)in_sizes; (void)n_in; (void)out_size; (void)ws_size;
    const float* src = (const float*)d_in[0];
    const float* Wq  = (const float*)d_in[1];
    const float* bq  = (const float*)d_in[2];
    const float* Wk  = (const float*)d_in[3];
    const float* bk  = (const float*)d_in[4];
    const float* Wv  = (const float*)d_in[5];
    const float* bv  = (const float*)d_in[6];
    const float* Wo  = (const float*)d_in[7];
    const float* bo  = (const float*)d_in[8];
    const float* W1  = (const float*)d_in[9];
    const float* b1  = (const float*)d_in[10];
    const float* W2  = (const float*)d_in[11];
    const float* b2  = (const float*)d_in[12];
    const float* g1  = (const float*)d_in[13];
    const float* be1 = (const float*)d_in[14];
    const float* g2  = (const float*)d_in[15];
    const float* be2 = (const float*)d_in[16];
    float* out = (float*)d_out;

    // ---- workspace layout (~77 MB peak) ----
    char* w = (char*)d_ws;
    u16* WqkvT = (u16*)w; w += (size_t)2304 * 768 * 2;
    u16* WoT   = (u16*)w; w += (size_t)768 * 768 * 2;
    u16* W1T   = (u16*)w; w += (size_t)D_FF * 768 * 2;
    u16* W2T   = (u16*)w; w += (size_t)768 * D_FF * 2;
    float* bqkv = (float*)w; w += 2304 * 4 + 64;
    char* A0 = w; w += (size_t)NROWS * 768 * 2;          // 12.58 MB
    char* A1 = w; w += (size_t)NROWS * 2304 * 2;         // 37.75 MB
    char* A2 = w; w += (size_t)NROWS * 768 * 2;          // 12.58 MB
    u16*   srcb  = (u16*)A0;    // blocked; dead after QKV gemm
    u16*   vtb   = (u16*)A0;    // alias: live during attention
    u16*   qkvb  = (u16*)A1;    // blocked; dead after attention
    float* sum   = (float*)A1;  // alias: out-proj f32 out
    u16*   attnb = (u16*)A2;    // row-major; dead after out-proj
    u16*   x1b   = (u16*)A2;    // alias: LN1 blocked bf16 out
    u16*   hb    = (u16*)A0;    // alias: blocked FFN hidden spans A0+A1

    const dim3 blk(256);
    const dim3 blk512(512);

    // single batched prologue launch (was 8 kernels)
    prep_kernel<<<dim3(9993), blk, 0, stream>>>(
        Wq, Wk, Wv, Wo, W1, W2, src, bq, bk, bv,
        WqkvT, WoT, W1T, W2T, srcb, bqkv);

    // fused QKV projection: 256x128 tiles (32x18 = 576 blocks)
    gemm_bt256<<<dim3(32, 18), blk512, 0, stream>>>(srcb, WqkvT, bqkv,
        qkvb, 2304, 768, FLAG_ABLK | FLAG_CBBLK);

    // V transpose, then flash attention (bh-major grid: wgid%8==bh%8 -> one XCD
    // owns all 16 q-blocks of a head -> K/V L2-resident)
    vt_kernel<<<dim3(32, 48), blk, 0, stream>>>(qkvb, vtb);
    attn_kernel<<<dim3(BSZ * N_HEAD, SEQ / 128), blk, 0, stream>>>(qkvb, vtb, attnb);

    // out-proj (+src residual) -> sum f32; LN1 -> x1b (blocked bf16)
    // 128x64 tiles: 768 blocks = 3/CU (r13's 256x64 variant was -2.8%)
    gemm_bt64<<<dim3(64, 12), blk, 0, stream>>>(attnb, 768, WoT, bo,
        src, nullptr, 768, sum, nullptr, 768, 768, 0);
    ln_kernel<<<dim3(NROWS), blk, 0, stream>>>(sum, nullptr, x1b, g1, be1);

    // FFN: hb = gelu(x1 @ W1 + b1) blocked (256x128 tiles, 32x24 = 768 blocks);
    // out = hb @ W2 + b2 + x1 (128x64 tiles)
    gemm_bt256<<<dim3(32, 24), blk512, 0, stream>>>(x1b, W1T, b1,
        hb, 3072, 768, FLAG_GELU | FLAG_ABLK | FLAG_CBBLK);
    gemm_bt64<<<dim3(64, 12), blk, 0, stream>>>(hb, 0, W2T, b2,
        nullptr, x1b, 768, out, nullptr, 768, 3072, FLAG_ABLK);

    // final LN in place
    ln_kernel<<<dim3(NROWS), blk, 0, stream>>>(out, out, nullptr, g2, be2);
}